// Round 8
// baseline (154.277 us; speedup 1.0000x reference)
//
#include <hip/hip_runtime.h>
#include <hip/hip_bf16.h>

#define DIMF 512
#define NHEAD 8
#define DHEAD 64
#define BATCH 2
#define SEQN 2048
#define SEQM 2048
#define FPS 40        // padded LDS row stride (u16): 32 data + 8 pad -> 2-way banks
#define QSCALE 0.18033688011112042f   // 0.125 * log2(e)

typedef unsigned short u16;
typedef __attribute__((ext_vector_type(8))) short bf16x8;
typedef __attribute__((ext_vector_type(4))) float f32x4;

static __device__ __forceinline__ u16 f2bf(float f) {
    unsigned u = __float_as_uint(f);
    u += 0x7FFF + ((u >> 16) & 1);      // RNE
    return (u16)(u >> 16);
}
static __device__ __forceinline__ u16 f2bf_fast(float f) {
    return (u16)((__float_as_uint(f) + 0x8000u) >> 16);
}

static __device__ __forceinline__
void load16(const u16* g, u16* l) {
    __builtin_amdgcn_global_load_lds(
        (const __attribute__((address_space(1))) void*)g,
        (__attribute__((address_space(3))) void*)l,
        16, 0, 0);
}

// ---------------------------------------------------------------------------
// weights fp32 -> bf16 (+ mask int -> bf16 {0,1})
// ---------------------------------------------------------------------------
__global__ __launch_bounds__(256)
void cvt_w(const float* __restrict__ wq, const float* __restrict__ wk,
           const float* __restrict__ wv, const float* __restrict__ wm,
           const int* __restrict__ mask,
           u16* __restrict__ wqb, u16* __restrict__ wkb,
           u16* __restrict__ wvb, u16* __restrict__ wmb,
           u16* __restrict__ maskbf)
{
    int i = (blockIdx.x * 256 + threadIdx.x) * 4;
    if (blockIdx.y == 4) {
        if (i < BATCH * SEQM) {
            int4 m4 = *(const int4*)&mask[i];
            *(ushort4*)&maskbf[i] = make_ushort4(m4.x ? 0x3F80 : 0, m4.y ? 0x3F80 : 0,
                                                 m4.z ? 0x3F80 : 0, m4.w ? 0x3F80 : 0);
        }
        return;
    }
    const float* in = (blockIdx.y == 0) ? wq : (blockIdx.y == 1) ? wk
                    : (blockIdx.y == 2) ? wv : wm;
    u16* out = (blockIdx.y == 0) ? wqb : (blockIdx.y == 1) ? wkb
             : (blockIdx.y == 2) ? wvb : wmb;
    if (i >= DIMF * DIMF) return;
    float4 v = *(const float4*)&in[i];
    *(ushort4*)&out[i] = make_ushort4(f2bf(v.x), f2bf(v.y), f2bf(v.z), f2bf(v.w));
}

// ---------------------------------------------------------------------------
// bf16 MFMA GEMM, 64x128 tile, 4 waves (2x2), wave 32x64 = 2x4 frags.
// A staged from fp32 (Xf, fused cvt) or bf16 (Xb). Padded LDS stride 40 u16.
// mode 0: q -> bf16 [B][H][n][d], (val+bias)*QSCALE (softmax+exp2 folded)
// mode 1: k -> bf16 [B][H][m][d]
// mode 2: V^T -> bf16 [B][H][d][m], masked rows zeroed, TRANSPOSED IN-BLOCK
//         through the staging LDS (dead after the K-loop) -- no vtr kernel.
// mode 3: fp32 row-major [4096][512]
// ---------------------------------------------------------------------------
__device__ __forceinline__
void gemm_mfma(const float* __restrict__ Xf, const u16* __restrict__ Xb,
               const u16* __restrict__ W, const float* __restrict__ bias,
               const int* __restrict__ msk, void* __restrict__ Out, int mode)
{
    __shared__ __align__(16) u16 SH[7680];   // As 64*FPS | Bs 128*FPS (15 KB)
    u16* As = SH;
    u16* Bs = SH + 64 * FPS;

    const int tid  = threadIdx.x;
    const int wave = tid >> 6;
    const int lane = tid & 63;
    const int l15  = lane & 15;
    const int quad = lane >> 4;
    const int wm = wave & 1, wn = wave >> 1;
    const int r0 = blockIdx.x * 64, c0 = blockIdx.y * 128;

    f32x4 acc[2][4] = {};

    const int br = tid >> 2, boct = tid & 3;        // B: rows br, br+64
    const int ar = tid >> 3, aseg = tid & 7;        // A fp32: rows ar, ar+32

    for (int k0 = 0; k0 < DIMF; k0 += 32) {
        bf16x8 bv0 = *(const bf16x8*)&W[(size_t)(c0 + br) * DIMF + k0 + boct * 8];
        bf16x8 bv1 = *(const bf16x8*)&W[(size_t)(c0 + br + 64) * DIMF + k0 + boct * 8];
        float4 a0, a1; bf16x8 av;
        if (Xf) {
            a0 = *(const float4*)&Xf[(size_t)(r0 + ar) * DIMF + k0 + aseg * 4];
            a1 = *(const float4*)&Xf[(size_t)(r0 + ar + 32) * DIMF + k0 + aseg * 4];
        } else {
            av = *(const bf16x8*)&Xb[(size_t)(r0 + br) * DIMF + k0 + boct * 8];
        }
        __syncthreads();
        if (Xf) {
            *(ushort4*)&As[ar * FPS + aseg * 4] =
                make_ushort4(f2bf(a0.x), f2bf(a0.y), f2bf(a0.z), f2bf(a0.w));
            *(ushort4*)&As[(ar + 32) * FPS + aseg * 4] =
                make_ushort4(f2bf(a1.x), f2bf(a1.y), f2bf(a1.z), f2bf(a1.w));
        } else {
            *(bf16x8*)&As[br * FPS + boct * 8] = av;
        }
        *(bf16x8*)&Bs[br * FPS + boct * 8] = bv0;
        *(bf16x8*)&Bs[(br + 64) * FPS + boct * 8] = bv1;
        __syncthreads();

        bf16x8 af[2], bf[4];
        #pragma unroll
        for (int mi = 0; mi < 2; ++mi)
            af[mi] = *(const bf16x8*)&As[(wm * 32 + mi * 16 + l15) * FPS + quad * 8];
        #pragma unroll
        for (int ni = 0; ni < 4; ++ni)
            bf[ni] = *(const bf16x8*)&Bs[(wn * 64 + ni * 16 + l15) * FPS + quad * 8];
        #pragma unroll
        for (int mi = 0; mi < 2; ++mi)
            #pragma unroll
            for (int ni = 0; ni < 4; ++ni)
                acc[mi][ni] = __builtin_amdgcn_mfma_f32_16x16x32_bf16(
                    af[mi], bf[ni], acc[mi][ni], 0, 0, 0);
    }

    float bb[4];
    #pragma unroll
    for (int ni = 0; ni < 4; ++ni)
        bb[ni] = bias[c0 + wn * 64 + ni * 16 + l15];

    if (mode == 2) {
        // in-block transpose: per head-half, waves with wn==hh dump their
        // masked 64n x 64d quarter into LDS [n][d]; all threads read [d][n]
        // columns and store V^T rows (m contiguous).
        u16* T = SH;                         // 64 x 72 u16 (9 KB of 15)
        const int b = r0 >> 11;
        const int n_base = r0 & (SEQN - 1);
        #pragma unroll
        for (int hh = 0; hh < 2; ++hh) {
            __syncthreads();
            if (wn == hh) {
                #pragma unroll
                for (int mi = 0; mi < 2; ++mi) {
                    const int rl = wm * 32 + mi * 16 + quad * 4;
                    int4 m4 = *(const int4*)&msk[b * SEQM + n_base + rl];
                    float mm[4];
                    mm[0] = m4.x ? 1.f : 0.f; mm[1] = m4.y ? 1.f : 0.f;
                    mm[2] = m4.z ? 1.f : 0.f; mm[3] = m4.w ? 1.f : 0.f;
                    #pragma unroll
                    for (int ni = 0; ni < 4; ++ni)
                        #pragma unroll
                        for (int r = 0; r < 4; ++r)
                            T[(rl + r) * 72 + ni * 16 + l15] =
                                f2bf((acc[mi][ni][r] + bb[ni]) * mm[r]);
                }
            }
            __syncthreads();
            const int d = tid >> 2, ms = (tid & 3) << 4;
            u16 tmp[16];
            #pragma unroll
            for (int j = 0; j < 16; ++j) tmp[j] = T[(ms + j) * 72 + d];
            const int hgl = (c0 >> 6) + hh;
            u16* dst = (u16*)Out + ((size_t)(b * NHEAD + hgl) * DHEAD + d) * SEQM
                       + n_base + ms;
            *(bf16x8*)&dst[0] = *(bf16x8*)&tmp[0];
            *(bf16x8*)&dst[8] = *(bf16x8*)&tmp[8];
        }
        return;
    }

    #pragma unroll
    for (int mi = 0; mi < 2; ++mi) {
        const int Rbase = r0 + wm * 32 + mi * 16 + quad * 4;   // +r, r=0..3
        const int b = Rbase >> 11;
        const int nb = Rbase & (SEQN - 1);
        #pragma unroll
        for (int ni = 0; ni < 4; ++ni) {
            const int C = c0 + wn * 64 + ni * 16 + l15;
            const int h = C >> 6, d = C & 63;
            if (mode == 0) {
                u16* ow = (u16*)Out;
                #pragma unroll
                for (int r = 0; r < 4; ++r)
                    ow[(((size_t)(b * NHEAD + h) * SEQN) + nb + r) * DHEAD + d] =
                        f2bf((acc[mi][ni][r] + bb[ni]) * QSCALE);
            } else if (mode == 1) {
                u16* ow = (u16*)Out;
                #pragma unroll
                for (int r = 0; r < 4; ++r)
                    ow[(((size_t)(b * NHEAD + h) * SEQN) + nb + r) * DHEAD + d] =
                        f2bf(acc[mi][ni][r] + bb[ni]);
            } else {
                float* ow = (float*)Out;
                #pragma unroll
                for (int r = 0; r < 4; ++r)
                    ow[(size_t)(Rbase + r) * DIMF + C] = acc[mi][ni][r] + bb[ni];
            }
        }
    }
}

__global__ __launch_bounds__(256, 4)
void qkv_proj(const float* __restrict__ x, const float* __restrict__ src,
              const u16* __restrict__ wqb, const float* __restrict__ bq,
              const u16* __restrict__ wkb, const float* __restrict__ bk,
              const u16* __restrict__ wvb, const float* __restrict__ bv,
              const int* __restrict__ mask,
              u16* __restrict__ qw, u16* __restrict__ kw, u16* __restrict__ vtw)
{
    const int z = blockIdx.z;
    const float* X = (z == 0) ? x : src;
    const u16* W = (z == 0) ? wqb : (z == 1) ? wkb : wvb;
    const float* B = (z == 0) ? bq : (z == 1) ? bk : bv;
    void* O = (z == 0) ? (void*)qw : (z == 1) ? (void*)kw : (void*)vtw;
    gemm_mfma(X, nullptr, W, B, mask, O, z);
}

__global__ __launch_bounds__(256, 4)
void out_proj(const u16* __restrict__ aggb, const u16* __restrict__ wmb,
              const float* __restrict__ bm, float* __restrict__ out)
{
    gemm_mfma(nullptr, aggb, wmb, bm, nullptr, (void*)out, 3);
}

// ---------------------------------------------------------------------------
// MFMA flash attention v4: 32 q-rows per wave.
// Block = (b, h, 64 q-rows); 4 waves = 2 q-groups(32q) x 2 m-halves(32m);
// grid 512. K/V^T staged by async global_load_lds into XOR-swizzled LDS
// (slot(row,oct) = row*8 + (oct^(row&7)) in 16B units; DMA lane permutes its
// global source octet -- coalescing preserved; frag reads 2-way max).
// af/vf fragment reads SHARED across the two 16-q groups -> LDS bytes per
// unit of work halved vs R7 (the measured bottleneck).
// Lean loop: p = exp2(s) (scale folded into q), no mask in loop (V rows
// pre-zeroed), l via mask-row MFMA -> lacc[qh][r] lands on O's rows.
// ---------------------------------------------------------------------------
__global__ __launch_bounds__(256, 2)
void flash_attn_mfma(const u16* __restrict__ q, const u16* __restrict__ k,
                     const u16* __restrict__ vt, const u16* __restrict__ maskbf,
                     u16* __restrict__ agg)
{
    __shared__ __align__(16) u16 SH[13312];   // Ks 4096 | Vts 4096 | Ps 5120 u16
    u16* Ks  = SH;
    u16* Vts = SH + 4096;
    u16* Ps  = SH + 8192;
    float* Osum = (float*)SH;                 // epilogue: [qg][32q][64d] = 16 KB
    float* Lsum = (float*)(SH + 8192);        // [qg][32q] (in dead Ps space)

    const int tid  = threadIdx.x;
    const int wave = tid >> 6;
    const int lane = tid & 63;
    const int l15  = lane & 15;
    const int quad = lane >> 4;
    const int qg = wave >> 1, mh = wave & 1;
    const int h = blockIdx.y, b = blockIdx.z;
    const int n0 = blockIdx.x * 64;
    const size_t hoff = (size_t)(b * NHEAD + h) * (size_t)SEQM * DHEAD;
    const u16* kb = k  + hoff;
    const u16* vb = vt + hoff;
    const u16* mb = maskbf + b * SEQM;

    // DMA geometry: group g covers rows 8g..8g+7; lane l -> row 8g+(l>>3),
    // source oct = (l&7)^((l>>3)&7), stored at lane-contiguous slot.
    const int dr   = lane >> 3;
    const int doct = (lane & 7) ^ (dr & 7);
    const int g0 = wave, g1 = 4 + wave;
    const u16* kq0 = kb + (size_t)(g0 * 8 + dr) * DHEAD + doct * 8;
    const u16* kq1 = kb + (size_t)(g1 * 8 + dr) * DHEAD + doct * 8;
    const u16* vq0 = vb + (size_t)(g0 * 8 + dr) * SEQM + doct * 8;
    const u16* vq1 = vb + (size_t)(g1 * 8 + dr) * SEQM + doct * 8;
    u16* kl0 = Ks  + g0 * 512;  u16* kl1 = Ks  + g1 * 512;
    u16* vl0 = Vts + g0 * 512;  u16* vl1 = Vts + g1 * 512;

    // Q B-frags (prescaled by 0.125*log2e): cols q = n0 + qg*32 + qh*16 + l15
    bf16x8 qf[2][2];
    #pragma unroll
    for (int qh = 0; qh < 2; ++qh) {
        const u16* qp = q + hoff + (size_t)(n0 + qg * 32 + qh * 16 + l15) * DHEAD
                        + quad * 8;
        qf[qh][0] = *(const bf16x8*)qp;
        qf[qh][1] = *(const bf16x8*)(qp + 32);
    }

    f32x4 O[2][4] = {};    // [qh][sd]: row q = quad*4+r, col d = 16*sd+l15
    f32x4 lacc[2] = {};    // lacc[qh][r] = partial l
    u16* Pw = Ps + wave * (32 * FPS);
    const int xoct = l15 & 7;

    for (int m0 = 0; m0 < SEQM; m0 += 64) {
        __syncthreads();
        load16(kq0 + (size_t)m0 * DHEAD, kl0);
        load16(kq1 + (size_t)m0 * DHEAD, kl1);
        load16(vq0 + m0, vl0);
        load16(vq1 + m0, vl1);
        __syncthreads();

        // S^T (this wave's 32-m half): rows m, cols q; af shared across qh
        f32x4 st[2][2] = {};
        #pragma unroll
        for (int sub = 0; sub < 2; ++sub) {
            const int mrow = 32 * mh + 16 * sub + l15;
            #pragma unroll
            for (int c = 0; c < 2; ++c) {
                const int oct = (4 * c + quad) ^ xoct;
                bf16x8 af = *(const bf16x8*)&Ks[mrow * 64 + oct * 8];
                #pragma unroll
                for (int qh = 0; qh < 2; ++qh)
                    st[qh][sub] = __builtin_amdgcn_mfma_f32_16x16x32_bf16(
                        af, qf[qh][c], st[qh][sub], 0, 0, 0);
            }
        }

        // p = 2^s, pack, P^T -> wave-private LDS (lgkm-ordered, no barrier)
        #pragma unroll
        for (int qh = 0; qh < 2; ++qh)
            #pragma unroll
            for (int sub = 0; sub < 2; ++sub) {
                ushort4 w4 = make_ushort4(
                    f2bf_fast(__builtin_amdgcn_exp2f(st[qh][sub][0])),
                    f2bf_fast(__builtin_amdgcn_exp2f(st[qh][sub][1])),
                    f2bf_fast(__builtin_amdgcn_exp2f(st[qh][sub][2])),
                    f2bf_fast(__builtin_amdgcn_exp2f(st[qh][sub][3])));
                *(ushort4*)&Pw[(qh * 16 + l15) * FPS + 16 * sub + 4 * quad] = w4;
            }

        // V frags + mask frag shared across qh
        bf16x8 vf[4];
        #pragma unroll
        for (int sd = 0; sd < 4; ++sd) {
            const int oct = (4 * mh + quad) ^ xoct;
            vf[sd] = *(const bf16x8*)&Vts[(16 * sd + l15) * 64 + oct * 8];
        }
        bf16x8 mf = *(const bf16x8*)&mb[m0 + 32 * mh + quad * 8];

        #pragma unroll
        for (int qh = 0; qh < 2; ++qh) {
            bf16x8 pf = *(const bf16x8*)&Pw[(qh * 16 + l15) * FPS + quad * 8];
            lacc[qh] = __builtin_amdgcn_mfma_f32_16x16x32_bf16(pf, mf, lacc[qh], 0, 0, 0);
            #pragma unroll
            for (int sd = 0; sd < 4; ++sd)
                O[qh][sd] = __builtin_amdgcn_mfma_f32_16x16x32_bf16(
                    pf, vf[sd], O[qh][sd], 0, 0, 0);
        }
    }

    // combine m-halves per q-group (LDS unioned over dead Ks/Vts/Ps)
    __syncthreads();
    if (mh == 1) {
        #pragma unroll
        for (int qh = 0; qh < 2; ++qh) {
            #pragma unroll
            for (int sd = 0; sd < 4; ++sd)
                #pragma unroll
                for (int r = 0; r < 4; ++r)
                    Osum[qg * 2048 + (qh * 16 + quad * 4 + r) * 64 + 16 * sd + l15]
                        = O[qh][sd][r];
            if (l15 == 0) {
                #pragma unroll
                for (int r = 0; r < 4; ++r)
                    Lsum[qg * 32 + qh * 16 + quad * 4 + r] = lacc[qh][r];
            }
        }
    }
    __syncthreads();
    if (mh == 0) {
        #pragma unroll
        for (int qh = 0; qh < 2; ++qh)
            #pragma unroll
            for (int r = 0; r < 4; ++r) {
                const float inv = 1.f /
                    (lacc[qh][r] + Lsum[qg * 32 + qh * 16 + quad * 4 + r]);
                const int n = n0 + qg * 32 + qh * 16 + quad * 4 + r;
                u16* ag = agg + ((size_t)b * SEQN + n) * DIMF + h * DHEAD + l15;
                #pragma unroll
                for (int sd = 0; sd < 4; ++sd)
                    ag[16 * sd] = f2bf((O[qh][sd][r] +
                        Osum[qg * 2048 + (qh * 16 + quad * 4 + r) * 64 + 16 * sd + l15])
                        * inv);
            }
    }
}

extern "C" void kernel_launch(void* const* d_in, const int* in_sizes, int n_in,
                              void* d_out, int out_size, void* d_ws, size_t ws_size,
                              hipStream_t stream)
{
    (void)in_sizes; (void)n_in; (void)out_size; (void)ws_size;
    const float* x      = (const float*)d_in[0];
    const float* source = (const float*)d_in[1];
    const int*   mask   = (const int*)  d_in[2];
    const float* Wq = (const float*)d_in[3]; const float* bq = (const float*)d_in[4];
    const float* Wk = (const float*)d_in[5]; const float* bk = (const float*)d_in[6];
    const float* Wv = (const float*)d_in[7]; const float* bv = (const float*)d_in[8];
    const float* Wm = (const float*)d_in[9]; const float* bm = (const float*)d_in[10];
    float* out = (float*)d_out;

    const size_t SZ = (size_t)BATCH * SEQN * DIMF;   // 2,097,152 elems
    const size_t WZ = (size_t)DIMF * DIMF;
    u16* qw   = (u16*)d_ws;          // bf16 [B][H][n][d] (xQSCALE, +bq)
    u16* kw   = qw  + SZ;            // bf16 [B][H][m][d]
    u16* vtw  = kw  + SZ;            // bf16 V^T [B][H][d][m], masked
    u16* aggb = vtw + SZ;            // bf16 [B][n][H*64+d]
    u16* wqb  = aggb + SZ;
    u16* wkb  = wqb + WZ;
    u16* wvb  = wkb + WZ;
    u16* wmb  = wvb + WZ;
    u16* maskbf = wmb + WZ;          // bf16 [B][M] {0,1}; ~19 MB total

    dim3 gcvt((WZ / 4 + 255) / 256, 5);
    cvt_w<<<gcvt, 256, 0, stream>>>(Wq, Wk, Wv, Wm, mask,
                                    wqb, wkb, wvb, wmb, maskbf);

    dim3 gproj(4096 / 64, 512 / 128, 3);    // 768 blocks
    qkv_proj<<<gproj, 256, 0, stream>>>(x, source, wqb, bq, wkb, bk, wvb, bv,
                                        mask, qw, kw, vtw);

    dim3 gattn(SEQN / 64, NHEAD, BATCH);    // 512 blocks, 2/CU
    flash_attn_mfma<<<gattn, 256, 0, stream>>>(qw, kw, vtw, maskbf, aggb);

    dim3 gout(4096 / 64, 512 / 128);        // 256 blocks
    out_proj<<<gout, 256, 0, stream>>>(aggb, wmb, bm, out);
}

// Round 9
// 147.768 us; speedup vs baseline: 1.0440x; 1.0440x over previous
//
#include <hip/hip_runtime.h>
#include <hip/hip_bf16.h>

#define DIMF 512
#define NHEAD 8
#define DHEAD 64
#define BATCH 2
#define SEQN 2048
#define SEQM 2048
#define FPS 40        // padded LDS row stride (u16): 32 data + 8 pad -> 2-way banks
#define QSCALE 0.18033688011112042f   // 0.125 * log2(e)

typedef unsigned short u16;
typedef __attribute__((ext_vector_type(8))) short bf16x8;
typedef __attribute__((ext_vector_type(4))) float f32x4;

static __device__ __forceinline__ u16 f2bf(float f) {
    unsigned u = __float_as_uint(f);
    u += 0x7FFF + ((u >> 16) & 1);      // RNE
    return (u16)(u >> 16);
}
static __device__ __forceinline__ u16 f2bf_fast(float f) {
    return (u16)((__float_as_uint(f) + 0x8000u) >> 16);
}

static __device__ __forceinline__
void load16(const u16* g, u16* l) {
    __builtin_amdgcn_global_load_lds(
        (const __attribute__((address_space(1))) void*)g,
        (__attribute__((address_space(3))) void*)l,
        16, 0, 0);
}

// ---------------------------------------------------------------------------
// weights fp32 -> bf16 (+ mask int -> bf16 {0,1})
// ---------------------------------------------------------------------------
__global__ __launch_bounds__(256)
void cvt_w(const float* __restrict__ wq, const float* __restrict__ wk,
           const float* __restrict__ wv, const float* __restrict__ wm,
           const int* __restrict__ mask,
           u16* __restrict__ wqb, u16* __restrict__ wkb,
           u16* __restrict__ wvb, u16* __restrict__ wmb,
           u16* __restrict__ maskbf)
{
    int i = (blockIdx.x * 256 + threadIdx.x) * 4;
    if (blockIdx.y == 4) {
        if (i < BATCH * SEQM) {
            int4 m4 = *(const int4*)&mask[i];
            *(ushort4*)&maskbf[i] = make_ushort4(m4.x ? 0x3F80 : 0, m4.y ? 0x3F80 : 0,
                                                 m4.z ? 0x3F80 : 0, m4.w ? 0x3F80 : 0);
        }
        return;
    }
    const float* in = (blockIdx.y == 0) ? wq : (blockIdx.y == 1) ? wk
                    : (blockIdx.y == 2) ? wv : wm;
    u16* out = (blockIdx.y == 0) ? wqb : (blockIdx.y == 1) ? wkb
             : (blockIdx.y == 2) ? wvb : wmb;
    if (i >= DIMF * DIMF) return;
    float4 v = *(const float4*)&in[i];
    *(ushort4*)&out[i] = make_ushort4(f2bf(v.x), f2bf(v.y), f2bf(v.z), f2bf(v.w));
}

// ---------------------------------------------------------------------------
// bf16 MFMA GEMM, 64x128 tile, 4 waves (2x2), wave 32x64 = 2x4 frags.
// A staged from fp32 (Xf, fused cvt) or bf16 (Xb). Padded LDS stride 40 u16.
// mode 0: q -> bf16 [B][H][n][d], (val+bias)*QSCALE (softmax+exp2 folded)
// mode 1: k -> bf16 [B][H][m][d]
// mode 2: V^T -> bf16 [B][H][d][m], masked rows zeroed, transposed in-block
// mode 3: fp32 row-major [4096][512]
// ---------------------------------------------------------------------------
__device__ __forceinline__
void gemm_mfma(const float* __restrict__ Xf, const u16* __restrict__ Xb,
               const u16* __restrict__ W, const float* __restrict__ bias,
               const int* __restrict__ msk, void* __restrict__ Out, int mode)
{
    __shared__ __align__(16) u16 SH[7680];   // As 64*FPS | Bs 128*FPS (15 KB)
    u16* As = SH;
    u16* Bs = SH + 64 * FPS;

    const int tid  = threadIdx.x;
    const int wave = tid >> 6;
    const int lane = tid & 63;
    const int l15  = lane & 15;
    const int quad = lane >> 4;
    const int wm = wave & 1, wn = wave >> 1;
    const int r0 = blockIdx.x * 64, c0 = blockIdx.y * 128;

    f32x4 acc[2][4] = {};

    const int br = tid >> 2, boct = tid & 3;        // B: rows br, br+64
    const int ar = tid >> 3, aseg = tid & 7;        // A fp32: rows ar, ar+32

    for (int k0 = 0; k0 < DIMF; k0 += 32) {
        bf16x8 bv0 = *(const bf16x8*)&W[(size_t)(c0 + br) * DIMF + k0 + boct * 8];
        bf16x8 bv1 = *(const bf16x8*)&W[(size_t)(c0 + br + 64) * DIMF + k0 + boct * 8];
        float4 a0, a1; bf16x8 av;
        if (Xf) {
            a0 = *(const float4*)&Xf[(size_t)(r0 + ar) * DIMF + k0 + aseg * 4];
            a1 = *(const float4*)&Xf[(size_t)(r0 + ar + 32) * DIMF + k0 + aseg * 4];
        } else {
            av = *(const bf16x8*)&Xb[(size_t)(r0 + br) * DIMF + k0 + boct * 8];
        }
        __syncthreads();
        if (Xf) {
            *(ushort4*)&As[ar * FPS + aseg * 4] =
                make_ushort4(f2bf(a0.x), f2bf(a0.y), f2bf(a0.z), f2bf(a0.w));
            *(ushort4*)&As[(ar + 32) * FPS + aseg * 4] =
                make_ushort4(f2bf(a1.x), f2bf(a1.y), f2bf(a1.z), f2bf(a1.w));
        } else {
            *(bf16x8*)&As[br * FPS + boct * 8] = av;
        }
        *(bf16x8*)&Bs[br * FPS + boct * 8] = bv0;
        *(bf16x8*)&Bs[(br + 64) * FPS + boct * 8] = bv1;
        __syncthreads();

        bf16x8 af[2], bf[4];
        #pragma unroll
        for (int mi = 0; mi < 2; ++mi)
            af[mi] = *(const bf16x8*)&As[(wm * 32 + mi * 16 + l15) * FPS + quad * 8];
        #pragma unroll
        for (int ni = 0; ni < 4; ++ni)
            bf[ni] = *(const bf16x8*)&Bs[(wn * 64 + ni * 16 + l15) * FPS + quad * 8];
        #pragma unroll
        for (int mi = 0; mi < 2; ++mi)
            #pragma unroll
            for (int ni = 0; ni < 4; ++ni)
                acc[mi][ni] = __builtin_amdgcn_mfma_f32_16x16x32_bf16(
                    af[mi], bf[ni], acc[mi][ni], 0, 0, 0);
    }

    float bb[4];
    #pragma unroll
    for (int ni = 0; ni < 4; ++ni)
        bb[ni] = bias[c0 + wn * 64 + ni * 16 + l15];

    if (mode == 2) {
        u16* T = SH;                         // 64 x 72 u16
        const int b = r0 >> 11;
        const int n_base = r0 & (SEQN - 1);
        #pragma unroll
        for (int hh = 0; hh < 2; ++hh) {
            __syncthreads();
            if (wn == hh) {
                #pragma unroll
                for (int mi = 0; mi < 2; ++mi) {
                    const int rl = wm * 32 + mi * 16 + quad * 4;
                    int4 m4 = *(const int4*)&msk[b * SEQM + n_base + rl];
                    float mm[4];
                    mm[0] = m4.x ? 1.f : 0.f; mm[1] = m4.y ? 1.f : 0.f;
                    mm[2] = m4.z ? 1.f : 0.f; mm[3] = m4.w ? 1.f : 0.f;
                    #pragma unroll
                    for (int ni = 0; ni < 4; ++ni)
                        #pragma unroll
                        for (int r = 0; r < 4; ++r)
                            T[(rl + r) * 72 + ni * 16 + l15] =
                                f2bf((acc[mi][ni][r] + bb[ni]) * mm[r]);
                }
            }
            __syncthreads();
            const int d = tid >> 2, ms = (tid & 3) << 4;
            u16 tmp[16];
            #pragma unroll
            for (int j = 0; j < 16; ++j) tmp[j] = T[(ms + j) * 72 + d];
            const int hgl = (c0 >> 6) + hh;
            u16* dst = (u16*)Out + ((size_t)(b * NHEAD + hgl) * DHEAD + d) * SEQM
                       + n_base + ms;
            *(bf16x8*)&dst[0] = *(bf16x8*)&tmp[0];
            *(bf16x8*)&dst[8] = *(bf16x8*)&tmp[8];
        }
        return;
    }

    #pragma unroll
    for (int mi = 0; mi < 2; ++mi) {
        const int Rbase = r0 + wm * 32 + mi * 16 + quad * 4;   // +r, r=0..3
        const int b = Rbase >> 11;
        const int nb = Rbase & (SEQN - 1);
        #pragma unroll
        for (int ni = 0; ni < 4; ++ni) {
            const int C = c0 + wn * 64 + ni * 16 + l15;
            const int h = C >> 6, d = C & 63;
            if (mode == 0) {
                u16* ow = (u16*)Out;
                #pragma unroll
                for (int r = 0; r < 4; ++r)
                    ow[(((size_t)(b * NHEAD + h) * SEQN) + nb + r) * DHEAD + d] =
                        f2bf((acc[mi][ni][r] + bb[ni]) * QSCALE);
            } else if (mode == 1) {
                u16* ow = (u16*)Out;
                #pragma unroll
                for (int r = 0; r < 4; ++r)
                    ow[(((size_t)(b * NHEAD + h) * SEQN) + nb + r) * DHEAD + d] =
                        f2bf(acc[mi][ni][r] + bb[ni]);
            } else {
                float* ow = (float*)Out;
                #pragma unroll
                for (int r = 0; r < 4; ++r)
                    ow[(size_t)(Rbase + r) * DIMF + C] = acc[mi][ni][r] + bb[ni];
            }
        }
    }
}

__global__ __launch_bounds__(256, 4)
void qkv_proj(const float* __restrict__ x, const float* __restrict__ src,
              const u16* __restrict__ wqb, const float* __restrict__ bq,
              const u16* __restrict__ wkb, const float* __restrict__ bk,
              const u16* __restrict__ wvb, const float* __restrict__ bv,
              const int* __restrict__ mask,
              u16* __restrict__ qw, u16* __restrict__ kw, u16* __restrict__ vtw)
{
    const int z = blockIdx.z;
    const float* X = (z == 0) ? x : src;
    const u16* W = (z == 0) ? wqb : (z == 1) ? wkb : wvb;
    const float* B = (z == 0) ? bq : (z == 1) ? bk : bv;
    void* O = (z == 0) ? (void*)qw : (z == 1) ? (void*)kw : (void*)vtw;
    gemm_mfma(X, nullptr, W, B, mask, O, z);
}

__global__ __launch_bounds__(256, 4)
void out_proj(const u16* __restrict__ aggb, const u16* __restrict__ wmb,
              const float* __restrict__ bm, float* __restrict__ out)
{
    gemm_mfma(nullptr, aggb, wmb, bm, nullptr, (void*)out, 3);
}

// ---------------------------------------------------------------------------
// MFMA flash attention v5: DOUBLE-BUFFERED DMA staging.
// R8 exposed the full global latency every tile (issue DMA -> barrier drain):
// 3300 cyc/iter observed vs ~600 cyc chain. Now tile t+1 is staged into the
// other LDS buffer right AFTER the barrier, so the vmcnt(0) drain at the next
// barrier waits on loads that had a full compute phase in flight.
// Block = 64 q-rows; 4 waves = 2 qg(32q) x 2 mh(32m); flat 512-block grid
// with XCD swizzle: XCD (bid&7) only touches (b,h) pairs {2xcd, 2xcd+1}
// -> 1 MB K/V^T per XCD L2 (was 8 MB across all heads > 4 MB L2).
// XOR-swizzled LDS slots; lean loop (exp2-folded q, mask-free, l via
// mask-row MFMA); mask frag register-pipelined alongside the DMA.
// ---------------------------------------------------------------------------
__global__ __launch_bounds__(256, 2)
void flash_attn_mfma(const u16* __restrict__ q, const u16* __restrict__ k,
                     const u16* __restrict__ vt, const u16* __restrict__ maskbf,
                     u16* __restrict__ agg)
{
    __shared__ __align__(16) u16 KsD[2][4096];    // 16 KB
    __shared__ __align__(16) u16 VtsD[2][4096];   // 16 KB
    __shared__ u16 Ps[4 * 32 * FPS];              // 10 KB
    float* Osum = (float*)&KsD[0][0];             // epilogue union: 16 KB
    float* Lsum = (float*)&VtsD[0][0];            // [qg][32q]

    const int tid  = threadIdx.x;
    const int wave = tid >> 6;
    const int lane = tid & 63;
    const int l15  = lane & 15;
    const int quad = lane >> 4;
    const int qg = wave >> 1, mh = wave & 1;

    // XCD swizzle: bid&7 = XCD (dispatch round-robins blocks over 8 XCDs)
    const int bid  = blockIdx.x;
    const int xcd  = bid & 7, slot = bid >> 3;        // slot 0..63
    const int pair = (xcd << 1) | (slot & 1);         // (b*8+h) 0..15
    const int b = pair >> 3, h = pair & 7;
    const int n0 = (slot >> 1) * 64;

    const size_t hoff = (size_t)(b * NHEAD + h) * (size_t)SEQM * DHEAD;
    const u16* kb = k  + hoff;
    const u16* vb = vt + hoff;
    const u16* mb = maskbf + b * SEQM;

    // DMA geometry: group g covers rows 8g..8g+7; lane l -> row 8g+(l>>3),
    // source oct = (l&7)^((l>>3)&7), stored lane-contiguously (XOR swizzle).
    const int dr   = lane >> 3;
    const int doct = (lane & 7) ^ (dr & 7);
    const int g0 = wave, g1 = 4 + wave;
    const u16* kq0 = kb + (size_t)(g0 * 8 + dr) * DHEAD + doct * 8;
    const u16* kq1 = kb + (size_t)(g1 * 8 + dr) * DHEAD + doct * 8;
    const u16* vq0 = vb + (size_t)(g0 * 8 + dr) * SEQM + doct * 8;
    const u16* vq1 = vb + (size_t)(g1 * 8 + dr) * SEQM + doct * 8;

    // Q B-frags (prescaled by 0.125*log2e): cols q = n0 + qg*32 + qh*16 + l15
    bf16x8 qf[2][2];
    #pragma unroll
    for (int qh = 0; qh < 2; ++qh) {
        const u16* qp = q + hoff + (size_t)(n0 + qg * 32 + qh * 16 + l15) * DHEAD
                        + quad * 8;
        qf[qh][0] = *(const bf16x8*)qp;
        qf[qh][1] = *(const bf16x8*)(qp + 32);
    }

    // prologue: tile 0 -> buffer 0; mask frag 0 -> register
    load16(kq0, &KsD[0][g0 * 512]);
    load16(kq1, &KsD[0][g1 * 512]);
    load16(vq0, &VtsD[0][g0 * 512]);
    load16(vq1, &VtsD[0][g1 * 512]);
    bf16x8 mf_nxt = *(const bf16x8*)&mb[32 * mh + quad * 8];

    f32x4 O[2][4] = {};    // [qh][sd]: row q = quad*4+r, col d = 16*sd+l15
    f32x4 lacc[2] = {};
    u16* Pw = Ps + wave * (32 * FPS);
    const int xoct = l15 & 7;

    for (int mt = 0; mt < SEQM / 64; ++mt) {
        const int cur = mt & 1;
        __syncthreads();   // drains vmcnt -> tile mt resident; prior reads done
        bf16x8 mf = mf_nxt;
        if (mt + 1 < SEQM / 64) {
            const int m1 = (mt + 1) * 64;
            const int nb = cur ^ 1;
            load16(kq0 + (size_t)m1 * DHEAD, &KsD[nb][g0 * 512]);
            load16(kq1 + (size_t)m1 * DHEAD, &KsD[nb][g1 * 512]);
            load16(vq0 + m1, &VtsD[nb][g0 * 512]);
            load16(vq1 + m1, &VtsD[nb][g1 * 512]);
            mf_nxt = *(const bf16x8*)&mb[m1 + 32 * mh + quad * 8];
        }
        const u16* Ks  = KsD[cur];
        const u16* Vts = VtsD[cur];

        // S^T (this wave's 32-m half): rows m, cols q; af shared across qh
        f32x4 st[2][2] = {};
        #pragma unroll
        for (int sub = 0; sub < 2; ++sub) {
            const int mrow = 32 * mh + 16 * sub + l15;
            #pragma unroll
            for (int c = 0; c < 2; ++c) {
                const int oct = (4 * c + quad) ^ xoct;
                bf16x8 af = *(const bf16x8*)&Ks[mrow * 64 + oct * 8];
                #pragma unroll
                for (int qh = 0; qh < 2; ++qh)
                    st[qh][sub] = __builtin_amdgcn_mfma_f32_16x16x32_bf16(
                        af, qf[qh][c], st[qh][sub], 0, 0, 0);
            }
        }

        // p = 2^s, pack, P^T -> wave-private LDS (lgkm-ordered, no barrier)
        #pragma unroll
        for (int qh = 0; qh < 2; ++qh)
            #pragma unroll
            for (int sub = 0; sub < 2; ++sub) {
                ushort4 w4 = make_ushort4(
                    f2bf_fast(__builtin_amdgcn_exp2f(st[qh][sub][0])),
                    f2bf_fast(__builtin_amdgcn_exp2f(st[qh][sub][1])),
                    f2bf_fast(__builtin_amdgcn_exp2f(st[qh][sub][2])),
                    f2bf_fast(__builtin_amdgcn_exp2f(st[qh][sub][3])));
                *(ushort4*)&Pw[(qh * 16 + l15) * FPS + 16 * sub + 4 * quad] = w4;
            }

        // V frags shared across qh
        bf16x8 vf[4];
        #pragma unroll
        for (int sd = 0; sd < 4; ++sd) {
            const int oct = (4 * mh + quad) ^ xoct;
            vf[sd] = *(const bf16x8*)&Vts[(16 * sd + l15) * 64 + oct * 8];
        }

        #pragma unroll
        for (int qh = 0; qh < 2; ++qh) {
            bf16x8 pf = *(const bf16x8*)&Pw[(qh * 16 + l15) * FPS + quad * 8];
            lacc[qh] = __builtin_amdgcn_mfma_f32_16x16x32_bf16(pf, mf, lacc[qh], 0, 0, 0);
            #pragma unroll
            for (int sd = 0; sd < 4; ++sd)
                O[qh][sd] = __builtin_amdgcn_mfma_f32_16x16x32_bf16(
                    pf, vf[sd], O[qh][sd], 0, 0, 0);
        }
    }

    // combine m-halves per q-group (LDS unioned over dead Ks/Vts)
    __syncthreads();
    if (mh == 1) {
        #pragma unroll
        for (int qh = 0; qh < 2; ++qh) {
            #pragma unroll
            for (int sd = 0; sd < 4; ++sd)
                #pragma unroll
                for (int r = 0; r < 4; ++r)
                    Osum[qg * 2048 + (qh * 16 + quad * 4 + r) * 64 + 16 * sd + l15]
                        = O[qh][sd][r];
            if (l15 == 0) {
                #pragma unroll
                for (int r = 0; r < 4; ++r)
                    Lsum[qg * 32 + qh * 16 + quad * 4 + r] = lacc[qh][r];
            }
        }
    }
    __syncthreads();
    if (mh == 0) {
        #pragma unroll
        for (int qh = 0; qh < 2; ++qh)
            #pragma unroll
            for (int r = 0; r < 4; ++r) {
                const float inv = 1.f /
                    (lacc[qh][r] + Lsum[qg * 32 + qh * 16 + quad * 4 + r]);
                const int n = n0 + qg * 32 + qh * 16 + quad * 4 + r;
                u16* ag = agg + ((size_t)b * SEQN + n) * DIMF + h * DHEAD + l15;
                #pragma unroll
                for (int sd = 0; sd < 4; ++sd)
                    ag[16 * sd] = f2bf((O[qh][sd][r] +
                        Osum[qg * 2048 + (qh * 16 + quad * 4 + r) * 64 + 16 * sd + l15])
                        * inv);
            }
    }
}

extern "C" void kernel_launch(void* const* d_in, const int* in_sizes, int n_in,
                              void* d_out, int out_size, void* d_ws, size_t ws_size,
                              hipStream_t stream)
{
    (void)in_sizes; (void)n_in; (void)out_size; (void)ws_size;
    const float* x      = (const float*)d_in[0];
    const float* source = (const float*)d_in[1];
    const int*   mask   = (const int*)  d_in[2];
    const float* Wq = (const float*)d_in[3]; const float* bq = (const float*)d_in[4];
    const float* Wk = (const float*)d_in[5]; const float* bk = (const float*)d_in[6];
    const float* Wv = (const float*)d_in[7]; const float* bv = (const float*)d_in[8];
    const float* Wm = (const float*)d_in[9]; const float* bm = (const float*)d_in[10];
    float* out = (float*)d_out;

    const size_t SZ = (size_t)BATCH * SEQN * DIMF;   // 2,097,152 elems
    const size_t WZ = (size_t)DIMF * DIMF;
    u16* qw   = (u16*)d_ws;          // bf16 [B][H][n][d] (xQSCALE, +bq)
    u16* kw   = qw  + SZ;            // bf16 [B][H][m][d]
    u16* vtw  = kw  + SZ;            // bf16 V^T [B][H][d][m], masked
    u16* aggb = vtw + SZ;            // bf16 [B][n][H*64+d]
    u16* wqb  = aggb + SZ;
    u16* wkb  = wqb + WZ;
    u16* wvb  = wkb + WZ;
    u16* wmb  = wvb + WZ;
    u16* maskbf = wmb + WZ;          // bf16 [B][M] {0,1}; ~19 MB total

    dim3 gcvt((WZ / 4 + 255) / 256, 5);
    cvt_w<<<gcvt, 256, 0, stream>>>(Wq, Wk, Wv, Wm, mask,
                                    wqb, wkb, wvb, wmb, maskbf);

    dim3 gproj(4096 / 64, 512 / 128, 3);    // 768 blocks
    qkv_proj<<<gproj, 256, 0, stream>>>(x, source, wqb, bq, wkb, bk, wvb, bv,
                                        mask, qw, kw, vtw);

    flash_attn_mfma<<<512, 256, 0, stream>>>(qw, kw, vtw, maskbf, aggb);

    dim3 gout(4096 / 64, 512 / 128);        // 256 blocks
    out_proj<<<gout, 256, 0, stream>>>(aggb, wmb, bm, out);
}

// Round 11
// 146.853 us; speedup vs baseline: 1.0506x; 1.0062x over previous
//
#include <hip/hip_runtime.h>
#include <hip/hip_bf16.h>

#define DIMF 512
#define NHEAD 8
#define DHEAD 64
#define BATCH 2
#define SEQN 2048
#define SEQM 2048
#define FPS 40        // padded LDS row stride (u16): 32 data + 8 pad -> 2-way banks
#define QSCALE 0.18033688011112042f   // 0.125 * log2(e)

typedef unsigned short u16;
typedef __attribute__((ext_vector_type(8))) short bf16x8;
typedef __attribute__((ext_vector_type(4))) float f32x4;

static __device__ __forceinline__ u16 f2bf(float f) {
    unsigned u = __float_as_uint(f);
    u += 0x7FFF + ((u >> 16) & 1);      // RNE
    return (u16)(u >> 16);
}
static __device__ __forceinline__ u16 f2bf_fast(float f) {
    return (u16)((__float_as_uint(f) + 0x8000u) >> 16);
}

static __device__ __forceinline__
void load16(const u16* g, u16* l) {
    __builtin_amdgcn_global_load_lds(
        (const __attribute__((address_space(1))) void*)g,
        (__attribute__((address_space(3))) void*)l,
        16, 0, 0);
}

// ---------------------------------------------------------------------------
// weights fp32 -> bf16 (+ mask int -> bf16 {0,1})
// ---------------------------------------------------------------------------
__global__ __launch_bounds__(256)
void cvt_w(const float* __restrict__ wq, const float* __restrict__ wk,
           const float* __restrict__ wv, const float* __restrict__ wm,
           const int* __restrict__ mask,
           u16* __restrict__ wqb, u16* __restrict__ wkb,
           u16* __restrict__ wvb, u16* __restrict__ wmb,
           u16* __restrict__ maskbf)
{
    int i = (blockIdx.x * 256 + threadIdx.x) * 4;
    if (blockIdx.y == 4) {
        if (i < BATCH * SEQM) {
            int4 m4 = *(const int4*)&mask[i];
            *(ushort4*)&maskbf[i] = make_ushort4(m4.x ? 0x3F80 : 0, m4.y ? 0x3F80 : 0,
                                                 m4.z ? 0x3F80 : 0, m4.w ? 0x3F80 : 0);
        }
        return;
    }
    const float* in = (blockIdx.y == 0) ? wq : (blockIdx.y == 1) ? wk
                    : (blockIdx.y == 2) ? wv : wm;
    u16* out = (blockIdx.y == 0) ? wqb : (blockIdx.y == 1) ? wkb
             : (blockIdx.y == 2) ? wvb : wmb;
    if (i >= DIMF * DIMF) return;
    float4 v = *(const float4*)&in[i];
    *(ushort4*)&out[i] = make_ushort4(f2bf(v.x), f2bf(v.y), f2bf(v.z), f2bf(v.w));
}

// ---------------------------------------------------------------------------
// bf16 MFMA GEMM v2: DOUBLE-BUFFERED, ONE barrier per K-step (the R9 GEMM
// exposed full global latency between two back-to-back barriers, 16x).
// iter kt: stage regs(kt+1) -> buf[kt+1 & 1]; issue loads(kt+2); compute
// buf[kt & 1]; barrier. Loads ride ~2 iterations before consumption.
// LDS buffer bases computed by offset (no LDS-pointer arrays: clang can't
// emit generic-pointer static initializers from addrspace(3)).
// 64x128 tile, 4 waves (2x2), wave 32x64 = 2x4 frags. A from fp32 (fused
// cvt) or bf16. Padded LDS stride 40 u16 (2-way banks).
// mode 0: q -> bf16 [B][H][n][d], (val+bias)*QSCALE (softmax+exp2 folded)
// mode 1: k -> bf16 [B][H][m][d]
// mode 2: V^T -> bf16 [B][H][d][m], masked rows zeroed, transposed in-block
// mode 3: fp32 row-major [4096][512]
// ---------------------------------------------------------------------------
#define ASZ (64 * FPS)
#define BSZ (128 * FPS)

__device__ __forceinline__
void gemm_mfma(const float* __restrict__ Xf, const u16* __restrict__ Xb,
               const u16* __restrict__ W, const float* __restrict__ bias,
               const int* __restrict__ msk, void* __restrict__ Out, int mode)
{
    __shared__ __align__(16) u16 SH[2 * ASZ + 2 * BSZ];   // 30 KB

    const int tid  = threadIdx.x;
    const int wave = tid >> 6;
    const int lane = tid & 63;
    const int l15  = lane & 15;
    const int quad = lane >> 4;
    const int wm = wave & 1, wn = wave >> 1;
    const int r0 = blockIdx.x * 64, c0 = blockIdx.y * 128;

    f32x4 acc[2][4] = {};

    const int br = tid >> 2, boct = tid & 3;        // B: rows br, br+64
    const int ar = tid >> 3, aseg = tid & 7;        // A fp32: rows ar, ar+32

    bf16x8 rb0, rb1, rab;
    float4 ra0, ra1;

    auto loadg = [&](int k0) {
        rb0 = *(const bf16x8*)&W[(size_t)(c0 + br) * DIMF + k0 + boct * 8];
        rb1 = *(const bf16x8*)&W[(size_t)(c0 + br + 64) * DIMF + k0 + boct * 8];
        if (Xf) {
            ra0 = *(const float4*)&Xf[(size_t)(r0 + ar) * DIMF + k0 + aseg * 4];
            ra1 = *(const float4*)&Xf[(size_t)(r0 + ar + 32) * DIMF + k0 + aseg * 4];
        } else {
            rab = *(const bf16x8*)&Xb[(size_t)(r0 + br) * DIMF + k0 + boct * 8];
        }
    };
    auto stage = [&](int buf) {
        u16* As = SH + buf * ASZ;
        u16* Bs = SH + 2 * ASZ + buf * BSZ;
        if (Xf) {
            *(ushort4*)&As[ar * FPS + aseg * 4] =
                make_ushort4(f2bf(ra0.x), f2bf(ra0.y), f2bf(ra0.z), f2bf(ra0.w));
            *(ushort4*)&As[(ar + 32) * FPS + aseg * 4] =
                make_ushort4(f2bf(ra1.x), f2bf(ra1.y), f2bf(ra1.z), f2bf(ra1.w));
        } else {
            *(bf16x8*)&As[br * FPS + boct * 8] = rab;
        }
        *(bf16x8*)&Bs[br * FPS + boct * 8] = rb0;
        *(bf16x8*)&Bs[(br + 64) * FPS + boct * 8] = rb1;
    };

    loadg(0);
    stage(0);
    loadg(32);
    __syncthreads();

    const int NK = DIMF / 32;   // 16
    for (int kt = 0; kt < NK; ++kt) {
        const int cur = kt & 1;
        if (kt + 1 < NK) stage(cur ^ 1);       // regs for kt+1 (vmcnt hidden 1 iter)
        if (kt + 2 < NK) loadg((kt + 2) * 32); // in flight through this compute
        const u16* As = SH + cur * ASZ;
        const u16* Bs = SH + 2 * ASZ + cur * BSZ;

        bf16x8 af[2], bf[4];
        #pragma unroll
        for (int mi = 0; mi < 2; ++mi)
            af[mi] = *(const bf16x8*)&As[(wm * 32 + mi * 16 + l15) * FPS + quad * 8];
        #pragma unroll
        for (int ni = 0; ni < 4; ++ni)
            bf[ni] = *(const bf16x8*)&Bs[(wn * 64 + ni * 16 + l15) * FPS + quad * 8];
        #pragma unroll
        for (int mi = 0; mi < 2; ++mi)
            #pragma unroll
            for (int ni = 0; ni < 4; ++ni)
                acc[mi][ni] = __builtin_amdgcn_mfma_f32_16x16x32_bf16(
                    af[mi], bf[ni], acc[mi][ni], 0, 0, 0);
        __syncthreads();   // one barrier/iter: buf[cur] reads done, buf[cur^1] full
    }

    float bb[4];
    #pragma unroll
    for (int ni = 0; ni < 4; ++ni)
        bb[ni] = bias[c0 + wn * 64 + ni * 16 + l15];

    if (mode == 2) {
        u16* T = SH;                         // 64 x 72 u16 (9 KB of 30)
        const int b = r0 >> 11;
        const int n_base = r0 & (SEQN - 1);
        #pragma unroll
        for (int hh = 0; hh < 2; ++hh) {
            __syncthreads();
            if (wn == hh) {
                #pragma unroll
                for (int mi = 0; mi < 2; ++mi) {
                    const int rl = wm * 32 + mi * 16 + quad * 4;
                    int4 m4 = *(const int4*)&msk[b * SEQM + n_base + rl];
                    float mm[4];
                    mm[0] = m4.x ? 1.f : 0.f; mm[1] = m4.y ? 1.f : 0.f;
                    mm[2] = m4.z ? 1.f : 0.f; mm[3] = m4.w ? 1.f : 0.f;
                    #pragma unroll
                    for (int ni = 0; ni < 4; ++ni)
                        #pragma unroll
                        for (int r = 0; r < 4; ++r)
                            T[(rl + r) * 72 + ni * 16 + l15] =
                                f2bf((acc[mi][ni][r] + bb[ni]) * mm[r]);
                }
            }
            __syncthreads();
            const int d = tid >> 2, ms = (tid & 3) << 4;
            u16 tmp[16];
            #pragma unroll
            for (int j = 0; j < 16; ++j) tmp[j] = T[(ms + j) * 72 + d];
            const int hgl = (c0 >> 6) + hh;
            u16* dst = (u16*)Out + ((size_t)(b * NHEAD + hgl) * DHEAD + d) * SEQM
                       + n_base + ms;
            *(bf16x8*)&dst[0] = *(bf16x8*)&tmp[0];
            *(bf16x8*)&dst[8] = *(bf16x8*)&tmp[8];
        }
        return;
    }

    #pragma unroll
    for (int mi = 0; mi < 2; ++mi) {
        const int Rbase = r0 + wm * 32 + mi * 16 + quad * 4;   // +r, r=0..3
        const int b = Rbase >> 11;
        const int nb = Rbase & (SEQN - 1);
        #pragma unroll
        for (int ni = 0; ni < 4; ++ni) {
            const int C = c0 + wn * 64 + ni * 16 + l15;
            const int h = C >> 6, d = C & 63;
            if (mode == 0) {
                u16* ow = (u16*)Out;
                #pragma unroll
                for (int r = 0; r < 4; ++r)
                    ow[(((size_t)(b * NHEAD + h) * SEQN) + nb + r) * DHEAD + d] =
                        f2bf((acc[mi][ni][r] + bb[ni]) * QSCALE);
            } else if (mode == 1) {
                u16* ow = (u16*)Out;
                #pragma unroll
                for (int r = 0; r < 4; ++r)
                    ow[(((size_t)(b * NHEAD + h) * SEQN) + nb + r) * DHEAD + d] =
                        f2bf(acc[mi][ni][r] + bb[ni]);
            } else {
                float* ow = (float*)Out;
                #pragma unroll
                for (int r = 0; r < 4; ++r)
                    ow[(size_t)(Rbase + r) * DIMF + C] = acc[mi][ni][r] + bb[ni];
            }
        }
    }
}

__global__ __launch_bounds__(256, 3)
void qkv_proj(const float* __restrict__ x, const float* __restrict__ src,
              const u16* __restrict__ wqb, const float* __restrict__ bq,
              const u16* __restrict__ wkb, const float* __restrict__ bk,
              const u16* __restrict__ wvb, const float* __restrict__ bv,
              const int* __restrict__ mask,
              u16* __restrict__ qw, u16* __restrict__ kw, u16* __restrict__ vtw)
{
    const int z = blockIdx.z;
    const float* X = (z == 0) ? x : src;
    const u16* W = (z == 0) ? wqb : (z == 1) ? wkb : wvb;
    const float* B = (z == 0) ? bq : (z == 1) ? bk : bv;
    void* O = (z == 0) ? (void*)qw : (z == 1) ? (void*)kw : (void*)vtw;
    gemm_mfma(X, nullptr, W, B, mask, O, z);
}

__global__ __launch_bounds__(256, 3)
void out_proj(const u16* __restrict__ aggb, const u16* __restrict__ wmb,
              const float* __restrict__ bm, float* __restrict__ out)
{
    gemm_mfma(nullptr, aggb, wmb, bm, nullptr, (void*)out, 3);
}

// ---------------------------------------------------------------------------
// MFMA flash attention v5 (unchanged from R9): double-buffered DMA staging,
// XCD-swizzled grid, XOR-swizzled LDS, lean loop (exp2-folded q, mask-free,
// l via mask-row MFMA), shuffle-free epilogue.
// ---------------------------------------------------------------------------
__global__ __launch_bounds__(256, 2)
void flash_attn_mfma(const u16* __restrict__ q, const u16* __restrict__ k,
                     const u16* __restrict__ vt, const u16* __restrict__ maskbf,
                     u16* __restrict__ agg)
{
    __shared__ __align__(16) u16 KsD[2][4096];    // 16 KB
    __shared__ __align__(16) u16 VtsD[2][4096];   // 16 KB
    __shared__ u16 Ps[4 * 32 * FPS];              // 10 KB
    float* Osum = (float*)&KsD[0][0];             // epilogue union: 16 KB
    float* Lsum = (float*)&VtsD[0][0];            // [qg][32q]

    const int tid  = threadIdx.x;
    const int wave = tid >> 6;
    const int lane = tid & 63;
    const int l15  = lane & 15;
    const int quad = lane >> 4;
    const int qg = wave >> 1, mh = wave & 1;

    // XCD swizzle: bid&7 = XCD (dispatch round-robins blocks over 8 XCDs)
    const int bid  = blockIdx.x;
    const int xcd  = bid & 7, slot = bid >> 3;        // slot 0..63
    const int pair = (xcd << 1) | (slot & 1);         // (b*8+h) 0..15
    const int b = pair >> 3, h = pair & 7;
    const int n0 = (slot >> 1) * 64;

    const size_t hoff = (size_t)(b * NHEAD + h) * (size_t)SEQM * DHEAD;
    const u16* kb = k  + hoff;
    const u16* vb = vt + hoff;
    const u16* mb = maskbf + b * SEQM;

    // DMA geometry: group g covers rows 8g..8g+7; lane l -> row 8g+(l>>3),
    // source oct = (l&7)^((l>>3)&7), stored lane-contiguously (XOR swizzle).
    const int dr   = lane >> 3;
    const int doct = (lane & 7) ^ (dr & 7);
    const int g0 = wave, g1 = 4 + wave;
    const u16* kq0 = kb + (size_t)(g0 * 8 + dr) * DHEAD + doct * 8;
    const u16* kq1 = kb + (size_t)(g1 * 8 + dr) * DHEAD + doct * 8;
    const u16* vq0 = vb + (size_t)(g0 * 8 + dr) * SEQM + doct * 8;
    const u16* vq1 = vb + (size_t)(g1 * 8 + dr) * SEQM + doct * 8;

    // Q B-frags (prescaled by 0.125*log2e): cols q = n0 + qg*32 + qh*16 + l15
    bf16x8 qf[2][2];
    #pragma unroll
    for (int qh = 0; qh < 2; ++qh) {
        const u16* qp = q + hoff + (size_t)(n0 + qg * 32 + qh * 16 + l15) * DHEAD
                        + quad * 8;
        qf[qh][0] = *(const bf16x8*)qp;
        qf[qh][1] = *(const bf16x8*)(qp + 32);
    }

    // prologue: tile 0 -> buffer 0; mask frag 0 -> register
    load16(kq0, &KsD[0][g0 * 512]);
    load16(kq1, &KsD[0][g1 * 512]);
    load16(vq0, &VtsD[0][g0 * 512]);
    load16(vq1, &VtsD[0][g1 * 512]);
    bf16x8 mf_nxt = *(const bf16x8*)&mb[32 * mh + quad * 8];

    f32x4 O[2][4] = {};    // [qh][sd]: row q = quad*4+r, col d = 16*sd+l15
    f32x4 lacc[2] = {};
    u16* Pw = Ps + wave * (32 * FPS);
    const int xoct = l15 & 7;

    for (int mt = 0; mt < SEQM / 64; ++mt) {
        const int cur = mt & 1;
        __syncthreads();   // drains vmcnt -> tile mt resident; prior reads done
        bf16x8 mf = mf_nxt;
        if (mt + 1 < SEQM / 64) {
            const int m1 = (mt + 1) * 64;
            const int nb = cur ^ 1;
            load16(kq0 + (size_t)m1 * DHEAD, &KsD[nb][g0 * 512]);
            load16(kq1 + (size_t)m1 * DHEAD, &KsD[nb][g1 * 512]);
            load16(vq0 + m1, &VtsD[nb][g0 * 512]);
            load16(vq1 + m1, &VtsD[nb][g1 * 512]);
            mf_nxt = *(const bf16x8*)&mb[m1 + 32 * mh + quad * 8];
        }
        const u16* Ks  = KsD[cur];
        const u16* Vts = VtsD[cur];

        // S^T (this wave's 32-m half): rows m, cols q; af shared across qh
        f32x4 st[2][2] = {};
        #pragma unroll
        for (int sub = 0; sub < 2; ++sub) {
            const int mrow = 32 * mh + 16 * sub + l15;
            #pragma unroll
            for (int c = 0; c < 2; ++c) {
                const int oct = (4 * c + quad) ^ xoct;
                bf16x8 af = *(const bf16x8*)&Ks[mrow * 64 + oct * 8];
                #pragma unroll
                for (int qh = 0; qh < 2; ++qh)
                    st[qh][sub] = __builtin_amdgcn_mfma_f32_16x16x32_bf16(
                        af, qf[qh][c], st[qh][sub], 0, 0, 0);
            }
        }

        // p = 2^s, pack, P^T -> wave-private LDS (lgkm-ordered, no barrier)
        #pragma unroll
        for (int qh = 0; qh < 2; ++qh)
            #pragma unroll
            for (int sub = 0; sub < 2; ++sub) {
                ushort4 w4 = make_ushort4(
                    f2bf_fast(__builtin_amdgcn_exp2f(st[qh][sub][0])),
                    f2bf_fast(__builtin_amdgcn_exp2f(st[qh][sub][1])),
                    f2bf_fast(__builtin_amdgcn_exp2f(st[qh][sub][2])),
                    f2bf_fast(__builtin_amdgcn_exp2f(st[qh][sub][3])));
                *(ushort4*)&Pw[(qh * 16 + l15) * FPS + 16 * sub + 4 * quad] = w4;
            }

        // V frags shared across qh
        bf16x8 vf[4];
        #pragma unroll
        for (int sd = 0; sd < 4; ++sd) {
            const int oct = (4 * mh + quad) ^ xoct;
            vf[sd] = *(const bf16x8*)&Vts[(16 * sd + l15) * 64 + oct * 8];
        }

        #pragma unroll
        for (int qh = 0; qh < 2; ++qh) {
            bf16x8 pf = *(const bf16x8*)&Pw[(qh * 16 + l15) * FPS + quad * 8];
            lacc[qh] = __builtin_amdgcn_mfma_f32_16x16x32_bf16(pf, mf, lacc[qh], 0, 0, 0);
            #pragma unroll
            for (int sd = 0; sd < 4; ++sd)
                O[qh][sd] = __builtin_amdgcn_mfma_f32_16x16x32_bf16(
                    pf, vf[sd], O[qh][sd], 0, 0, 0);
        }
    }

    // combine m-halves per q-group (LDS unioned over dead Ks/Vts)
    __syncthreads();
    if (mh == 1) {
        #pragma unroll
        for (int qh = 0; qh < 2; ++qh) {
            #pragma unroll
            for (int sd = 0; sd < 4; ++sd)
                #pragma unroll
                for (int r = 0; r < 4; ++r)
                    Osum[qg * 2048 + (qh * 16 + quad * 4 + r) * 64 + 16 * sd + l15]
                        = O[qh][sd][r];
            if (l15 == 0) {
                #pragma unroll
                for (int r = 0; r < 4; ++r)
                    Lsum[qg * 32 + qh * 16 + quad * 4 + r] = lacc[qh][r];
            }
        }
    }
    __syncthreads();
    if (mh == 0) {
        #pragma unroll
        for (int qh = 0; qh < 2; ++qh)
            #pragma unroll
            for (int r = 0; r < 4; ++r) {
                const float inv = 1.f /
                    (lacc[qh][r] + Lsum[qg * 32 + qh * 16 + quad * 4 + r]);
                const int n = n0 + qg * 32 + qh * 16 + quad * 4 + r;
                u16* ag = agg + ((size_t)b * SEQN + n) * DIMF + h * DHEAD + l15;
                #pragma unroll
                for (int sd = 0; sd < 4; ++sd)
                    ag[16 * sd] = f2bf((O[qh][sd][r] +
                        Osum[qg * 2048 + (qh * 16 + quad * 4 + r) * 64 + 16 * sd + l15])
                        * inv);
            }
    }
}

extern "C" void kernel_launch(void* const* d_in, const int* in_sizes, int n_in,
                              void* d_out, int out_size, void* d_ws, size_t ws_size,
                              hipStream_t stream)
{
    (void)in_sizes; (void)n_in; (void)out_size; (void)ws_size;
    const float* x      = (const float*)d_in[0];
    const float* source = (const float*)d_in[1];
    const int*   mask   = (const int*)  d_in[2];
    const float* Wq = (const float*)d_in[3]; const float* bq = (const float*)d_in[4];
    const float* Wk = (const float*)d_in[5]; const float* bk = (const float*)d_in[6];
    const float* Wv = (const float*)d_in[7]; const float* bv = (const float*)d_in[8];
    const float* Wm = (const float*)d_in[9]; const float* bm = (const float*)d_in[10];
    float* out = (float*)d_out;

    const size_t SZ = (size_t)BATCH * SEQN * DIMF;   // 2,097,152 elems
    const size_t WZ = (size_t)DIMF * DIMF;
    u16* qw   = (u16*)d_ws;          // bf16 [B][H][n][d] (xQSCALE, +bq)
    u16* kw   = qw  + SZ;            // bf16 [B][H][m][d]
    u16* vtw  = kw  + SZ;            // bf16 V^T [B][H][d][m], masked
    u16* aggb = vtw + SZ;            // bf16 [B][n][H*64+d]
    u16* wqb  = aggb + SZ;
    u16* wkb  = wqb + WZ;
    u16* wvb  = wkb + WZ;
    u16* wmb  = wvb + WZ;
    u16* maskbf = wmb + WZ;          // bf16 [B][M] {0,1}; ~19 MB total

    dim3 gcvt((WZ / 4 + 255) / 256, 5);
    cvt_w<<<gcvt, 256, 0, stream>>>(Wq, Wk, Wv, Wm, mask,
                                    wqb, wkb, wvb, wmb, maskbf);

    dim3 gproj(4096 / 64, 512 / 128, 3);    // 768 blocks
    qkv_proj<<<gproj, 256, 0, stream>>>(x, source, wqb, bq, wkb, bk, wvb, bv,
                                        mask, qw, kw, vtw);

    flash_attn_mfma<<<512, 256, 0, stream>>>(qw, kw, vtw, maskbf, aggb);

    dim3 gout(4096 / 64, 512 / 128);        // 256 blocks
    out_proj<<<gout, 256, 0, stream>>>(aggb, wmb, bm, out);
}